// Round 2
// baseline (469.134 us; speedup 1.0000x reference)
//
#include <hip/hip_runtime.h>
#include <hip/hip_bf16.h>

#define EPS 1e-5f

// Problem sizes (fixed by setup_inputs)
static constexpr int BB = 4, NN = 256;            // batch, spatial N
// layer widths: 512 (a||bp stacked), 128, 64

// ---------------- workspace layout (bytes) ----------------
static constexpr size_t OFF_FT    = 0;             // fT[b][c][n]  f32  (4*256*256)
static constexpr size_t OFF_W1T   = 1048576;       // W1T[c][o512] f32
static constexpr size_t OFF_W2T   = 1572864;       // W2T[c][o128] f32
static constexpr size_t OFF_W3T   = 1703936;       // W3T[c][o64]  f32
static constexpr size_t OFF_AB    = 1736704;       // ab[b][o512][n] f32
static constexpr size_t OFF_S1    = 3833856;       // s1[256]
static constexpr size_t OFF_T1    = 3834880;       // t1[256]
static constexpr size_t OFF_STATS = 3835904;       // sum2[128],sumsq2[128],sum3[64],sumsq3[64] = 1536B (memset 0)
static constexpr size_t OFF_S2    = 3837440;
static constexpr size_t OFF_T2    = 3837952;
static constexpr size_t OFF_S3    = 3838464;
static constexpr size_t OFF_T3    = 3838720;
static constexpr size_t OFF_H2    = 4194304;       // bf16 4*128*256*256 = 64MB
static constexpr size_t OFF_H3    = 71303168;      // bf16 4*64*256*256  = 32MB
// total = 104857600 bytes (100 MB)

static __device__ inline float bfu2f(unsigned short u) {
    return __uint_as_float(((unsigned int)u) << 16);
}
static __device__ inline unsigned short f2bfu(float f) {
    unsigned int u = __float_as_uint(f);
    unsigned int r = u + 0x7fffu + ((u >> 16) & 1u);   // RNE
    return (unsigned short)(r >> 16);
}

// Block-wide sum over 256 threads (4 waves). Returns total to ALL threads.
static __device__ inline float blockReduce256(float v, float* sred) {
    #pragma unroll
    for (int off = 32; off > 0; off >>= 1) v += __shfl_down(v, off);
    int lane = threadIdx.x & 63, w = threadIdx.x >> 6;
    __syncthreads();                 // protect sred reuse across calls
    if (lane == 0) sred[w] = v;
    __syncthreads();
    return sred[0] + sred[1] + sred[2] + sred[3];
}

// ---------------- K0: pair-mean + transpose -> fT[b][c][n] ----------------
__global__ void k0_pairmean_T(const float* __restrict__ feats, float* __restrict__ fT) {
    __shared__ float s[64][65];
    int b = blockIdx.x >> 2;
    int n0 = (blockIdx.x & 3) * 64;
    int tid = threadIdx.x;
    const float* fb = feats + (size_t)b * 513 * 256;
    for (int c0 = 0; c0 < 256; c0 += 64) {
        for (int idx = tid; idx < 64 * 64; idx += 256) {
            int n = idx >> 6, c = idx & 63;
            const float* r = fb + (size_t)(1 + 2 * (n0 + n)) * 256 + c0 + c;
            s[n][c] = 0.5f * (r[0] + r[256]);
        }
        __syncthreads();
        for (int idx = tid; idx < 64 * 64; idx += 256) {
            int c = idx >> 6, n = idx & 63;
            fT[((size_t)b * 256 + c0 + c) * 256 + n0 + n] = s[n][c];
        }
        __syncthreads();
    }
}

// ---------------- K_t: transpose weights ----------------
// W1T[c][o], o in [0,512): o<256 -> W1[o][c] (a-part), else W1[o-256][256+c] (b-part)
__global__ void kt_transposeW(const float* __restrict__ W1, const float* __restrict__ W2,
                              const float* __restrict__ W3, float* __restrict__ W1T,
                              float* __restrict__ W2T, float* __restrict__ W3T) {
    int idx = blockIdx.x * 256 + threadIdx.x;
    if (idx < 131072) {
        int c = idx >> 9, o = idx & 511;
        W1T[idx] = (o < 256) ? W1[(size_t)o * 512 + c] : W1[(size_t)(o - 256) * 512 + 256 + c];
    } else if (idx < 131072 + 32768) {
        int j = idx - 131072; int c = j >> 7, o = j & 127;
        W2T[j] = W2[(size_t)o * 256 + c];
    } else if (idx < 131072 + 32768 + 8192) {
        int j = idx - 163840; int c = j >> 6, o = j & 63;
        W3T[j] = W3[(size_t)o * 128 + c];
    }
}

// ---------------- K1: ab[b][o512][n] = sum_c W1T[c][o] * fT[b][c][n] ----------------
__global__ __launch_bounds__(256) void k1_gemm(const float* __restrict__ W1T,
                                               const float* __restrict__ fT,
                                               float* __restrict__ ab) {
    __shared__ float sW[64][68];
    __shared__ float sF[64][68];
    int tid = threadIdx.x;
    int b = blockIdx.x >> 2, n0 = (blockIdx.x & 3) * 64;
    int o0 = blockIdx.y * 64;
    int jq = tid & 15, og = tid >> 4;
    float acc[4][4] = {};
    for (int c0 = 0; c0 < 256; c0 += 64) {
        for (int idx = tid; idx < 64 * 64; idx += 256) {
            int c = idx >> 6, o = idx & 63;
            sW[c][o] = W1T[(size_t)(c0 + c) * 512 + o0 + o];
        }
        for (int idx = tid; idx < 64 * 64; idx += 256) {
            int c = idx >> 6, n = idx & 63;
            sF[c][n] = fT[((size_t)b * 256 + c0 + c) * 256 + n0 + n];
        }
        __syncthreads();
        #pragma unroll 8
        for (int c = 0; c < 64; ++c) {
            float4 rv = *(const float4*)&sF[c][jq * 4];
            float4 wv = *(const float4*)&sW[c][og * 4];
            float rr[4] = {rv.x, rv.y, rv.z, rv.w};
            float ww[4] = {wv.x, wv.y, wv.z, wv.w};
            #pragma unroll
            for (int m = 0; m < 4; ++m)
                #pragma unroll
                for (int w = 0; w < 4; ++w) acc[m][w] += ww[m] * rr[w];
        }
        __syncthreads();
    }
    for (int m = 0; m < 4; ++m) {
        int o = o0 + og * 4 + m;
        float4 v = {acc[m][0], acc[m][1], acc[m][2], acc[m][3]};
        *(float4*)&ab[((size_t)b * 512 + o) * 256 + n0 + jq * 4] = v;
    }
}

// ---------------- K1b: analytic BN1 stats -> s1,t1 ----------------
// h1[b,c,i,j] = a[b,c,i] + bp[b,c,j] (+b1, which cancels in BN)
__global__ void k1b_stats(const float* __restrict__ ab, const float* __restrict__ g1,
                          const float* __restrict__ be1, float* __restrict__ s1,
                          float* __restrict__ t1) {
    __shared__ float sred[4];
    int c = blockIdx.x, tid = threadIdx.x;
    float msum = 0.f, e2sum = 0.f;
    for (int b = 0; b < 4; ++b) {
        float va = ab[((size_t)b * 512 + c) * 256 + tid];
        float vb = ab[((size_t)b * 512 + 256 + c) * 256 + tid];
        float Sa = blockReduce256(va, sred);
        float Qa = blockReduce256(va * va, sred);
        float Sb = blockReduce256(vb, sred);
        float Qb = blockReduce256(vb * vb, sred);
        float ma = Sa * (1.f / 256.f), mb = Sb * (1.f / 256.f);
        msum += ma + mb;
        e2sum += Qa * (1.f / 256.f) + Qb * (1.f / 256.f) + 2.f * ma * mb;
    }
    if (tid == 0) {
        float m = msum * 0.25f, e2 = e2sum * 0.25f;
        float var = e2 - m * m;
        float s = g1[c] * rsqrtf(var + EPS);
        s1[c] = s;
        t1[c] = be1[c] - m * s;
    }
}

// ---------------- K2: h2 = W2 @ relu(bn1(a_i + bp_j)), h2 bf16 ----------------
__global__ __launch_bounds__(256) void k2_gemm(const float* __restrict__ ab,
                                               const float* __restrict__ W2T,
                                               const float* __restrict__ s1,
                                               const float* __restrict__ t1,
                                               unsigned short* __restrict__ h2) {
    __shared__ float sW[64][136];
    __shared__ float sF[64][68];
    __shared__ float sAA[256], sSS[256];
    int tid = threadIdx.x;
    int j0 = blockIdx.x * 64, i = blockIdx.y, b = blockIdx.z;
    {
        int c = tid;
        float av = ab[((size_t)b * 512 + c) * 256 + i];
        float s = s1[c];
        sAA[c] = av * s + t1[c];
        sSS[c] = s;
    }
    __syncthreads();
    int jq = tid & 15, og = tid >> 4;
    float acc[8][4] = {};
    const float* bpbase = ab + ((size_t)b * 512 + 256) * 256;
    for (int c0 = 0; c0 < 256; c0 += 64) {
        for (int idx = tid; idx < 64 * 128; idx += 256) {
            int c = idx >> 7, o = idx & 127;
            sW[c][o] = W2T[(size_t)(c0 + c) * 128 + o];
        }
        for (int idx = tid; idx < 64 * 64; idx += 256) {
            int cc = idx >> 6, jj = idx & 63;
            int c = c0 + cc;
            float bpv = bpbase[(size_t)c * 256 + j0 + jj];
            sF[cc][jj] = fmaxf(sAA[c] + bpv * sSS[c], 0.f);
        }
        __syncthreads();
        #pragma unroll 4
        for (int c = 0; c < 64; ++c) {
            float4 rv = *(const float4*)&sF[c][jq * 4];
            float4 w0 = *(const float4*)&sW[c][og * 8];
            float4 w1 = *(const float4*)&sW[c][og * 8 + 4];
            float rr[4] = {rv.x, rv.y, rv.z, rv.w};
            float ww[8] = {w0.x, w0.y, w0.z, w0.w, w1.x, w1.y, w1.z, w1.w};
            #pragma unroll
            for (int m = 0; m < 8; ++m)
                #pragma unroll
                for (int w = 0; w < 4; ++w) acc[m][w] += ww[m] * rr[w];
        }
        __syncthreads();
    }
    for (int m = 0; m < 8; ++m) {
        int o = og * 8 + m;
        ushort4 v;
        v.x = f2bfu(acc[m][0]); v.y = f2bfu(acc[m][1]);
        v.z = f2bfu(acc[m][2]); v.w = f2bfu(acc[m][3]);
        *(ushort4*)&h2[(((size_t)b * 128 + o) * 256 + i) * 256 + j0 + jq * 4] = v;
    }
}

// ---------------- kstats: per-channel sum/sumsq over bf16 planes ----------------
__global__ void kstats(const unsigned short* __restrict__ h, float* __restrict__ sum,
                       float* __restrict__ sumsq, int C) {
    __shared__ float sred[4];
    int p = blockIdx.x;
    int o = p % C;
    const unsigned short* base = h + (size_t)p * 65536;
    int tid = threadIdx.x;
    float s = 0.f, q = 0.f;
    for (int it = 0; it < 32; ++it) {
        uint4 v = *(const uint4*)(base + ((size_t)it * 256 + tid) * 8);
        unsigned int wv[4] = {v.x, v.y, v.z, v.w};
        #pragma unroll
        for (int k = 0; k < 4; ++k) {
            float f0 = __uint_as_float(wv[k] << 16);
            float f1 = __uint_as_float(wv[k] & 0xffff0000u);
            s += f0 + f1;
            q += f0 * f0 + f1 * f1;
        }
    }
    s = blockReduce256(s, sred);
    q = blockReduce256(q, sred);
    if (tid == 0) {
        atomicAdd(&sum[o], s);
        atomicAdd(&sumsq[o], q);
    }
}

// ---------------- bn params from sums ----------------
__global__ void kbnparam(const float* __restrict__ sum, const float* __restrict__ sumsq,
                         const float* __restrict__ g, const float* __restrict__ be,
                         float* __restrict__ s, float* __restrict__ t, int C, float invc) {
    int o = threadIdx.x;
    if (o < C) {
        float mean = sum[o] * invc;
        float var = sumsq[o] * invc - mean * mean;
        float sc = g[o] * rsqrtf(var + EPS);
        s[o] = sc;
        t[o] = be[o] - mean * sc;
    }
}

// ---------------- K3: h3 = W3 @ relu(bn2(h2)), bf16 ----------------
__global__ __launch_bounds__(256) void k3_gemm(const unsigned short* __restrict__ h2,
                                               const float* __restrict__ W3T,
                                               const float* __restrict__ s2,
                                               const float* __restrict__ t2,
                                               unsigned short* __restrict__ h3) {
    __shared__ float sW[64][68];
    __shared__ float sF[64][68];
    __shared__ float sS[128], sT[128];
    int tid = threadIdx.x;
    int j0 = blockIdx.x * 64, i = blockIdx.y, b = blockIdx.z;
    if (tid < 128) { sS[tid] = s2[tid]; sT[tid] = t2[tid]; }
    __syncthreads();
    int jq = tid & 15, og = tid >> 4;
    float acc[4][4] = {};
    for (int c0 = 0; c0 < 128; c0 += 64) {
        for (int idx = tid; idx < 64 * 64; idx += 256) {
            int c = idx >> 6, o = idx & 63;
            sW[c][o] = W3T[(size_t)(c0 + c) * 64 + o];
        }
        for (int idx = tid; idx < 64 * 64; idx += 256) {
            int cc = idx >> 6, jj = idx & 63;
            int c = c0 + cc;
            float hv = bfu2f(h2[(((size_t)b * 128 + c) * 256 + i) * 256 + j0 + jj]);
            sF[cc][jj] = fmaxf(hv * sS[c] + sT[c], 0.f);
        }
        __syncthreads();
        #pragma unroll 8
        for (int c = 0; c < 64; ++c) {
            float4 rv = *(const float4*)&sF[c][jq * 4];
            float4 wv = *(const float4*)&sW[c][og * 4];
            float rr[4] = {rv.x, rv.y, rv.z, rv.w};
            float ww[4] = {wv.x, wv.y, wv.z, wv.w};
            #pragma unroll
            for (int m = 0; m < 4; ++m)
                #pragma unroll
                for (int w = 0; w < 4; ++w) acc[m][w] += ww[m] * rr[w];
        }
        __syncthreads();
    }
    for (int m = 0; m < 4; ++m) {
        int o = og * 4 + m;
        ushort4 v;
        v.x = f2bfu(acc[m][0]); v.y = f2bfu(acc[m][1]);
        v.z = f2bfu(acc[m][2]); v.w = f2bfu(acc[m][3]);
        *(ushort4*)&h3[(((size_t)b * 64 + o) * 256 + i) * 256 + j0 + jq * 4] = v;
    }
}

// ---------------- K4: out = W4 @ relu(bn3(h3)) + b4 ----------------
__global__ __launch_bounds__(256) void k4_final(const unsigned short* __restrict__ h3,
                                                const float* __restrict__ W4,
                                                const float* __restrict__ s3,
                                                const float* __restrict__ t3,
                                                const float* __restrict__ b4,
                                                float* __restrict__ out) {
    __shared__ float sw[64], ss[64], st[64];
    int i = blockIdx.x, b = blockIdx.y;
    int tid = threadIdx.x;
    if (tid < 64) { sw[tid] = W4[tid]; ss[tid] = s3[tid]; st[tid] = t3[tid]; }
    __syncthreads();
    float acc = 0.f;
    #pragma unroll 4
    for (int c = 0; c < 64; ++c) {
        float hv = bfu2f(h3[(((size_t)b * 64 + c) * 256 + i) * 256 + tid]);
        acc += sw[c] * fmaxf(hv * ss[c] + st[c], 0.f);
    }
    out[((size_t)b * 256 + i) * 256 + tid] = acc + b4[0];
}

extern "C" void kernel_launch(void* const* d_in, const int* in_sizes, int n_in,
                              void* d_out, int out_size, void* d_ws, size_t ws_size,
                              hipStream_t stream) {
    const float* feats = (const float*)d_in[0];
    const float* W1  = (const float*)d_in[1];
    const float* g1  = (const float*)d_in[3];
    const float* be1 = (const float*)d_in[4];
    const float* W2  = (const float*)d_in[5];
    const float* g2  = (const float*)d_in[7];
    const float* be2 = (const float*)d_in[8];
    const float* W3  = (const float*)d_in[9];
    const float* g3  = (const float*)d_in[11];
    const float* be3 = (const float*)d_in[12];
    const float* W4  = (const float*)d_in[13];
    const float* b4  = (const float*)d_in[14];

    char* ws = (char*)d_ws;
    float* fT   = (float*)(ws + OFF_FT);
    float* W1T  = (float*)(ws + OFF_W1T);
    float* W2T  = (float*)(ws + OFF_W2T);
    float* W3T  = (float*)(ws + OFF_W3T);
    float* ab   = (float*)(ws + OFF_AB);
    float* s1   = (float*)(ws + OFF_S1);
    float* t1   = (float*)(ws + OFF_T1);
    float* sum2   = (float*)(ws + OFF_STATS);
    float* sumsq2 = (float*)(ws + OFF_STATS + 512);
    float* sum3   = (float*)(ws + OFF_STATS + 1024);
    float* sumsq3 = (float*)(ws + OFF_STATS + 1280);
    float* s2 = (float*)(ws + OFF_S2);
    float* t2 = (float*)(ws + OFF_T2);
    float* s3 = (float*)(ws + OFF_S3);
    float* t3 = (float*)(ws + OFF_T3);
    unsigned short* h2 = (unsigned short*)(ws + OFF_H2);
    unsigned short* h3 = (unsigned short*)(ws + OFF_H3);
    float* out = (float*)d_out;

    hipMemsetAsync(ws + OFF_STATS, 0, 1536, stream);

    k0_pairmean_T<<<16, 256, 0, stream>>>(feats, fT);
    kt_transposeW<<<672, 256, 0, stream>>>(W1, W2, W3, W1T, W2T, W3T);
    k1_gemm<<<dim3(16, 8), 256, 0, stream>>>(W1T, fT, ab);
    k1b_stats<<<256, 256, 0, stream>>>(ab, g1, be1, s1, t1);
    k2_gemm<<<dim3(4, 256, 4), 256, 0, stream>>>(ab, W2T, s1, t1, h2);
    kstats<<<512, 256, 0, stream>>>(h2, sum2, sumsq2, 128);
    kbnparam<<<1, 128, 0, stream>>>(sum2, sumsq2, g2, be2, s2, t2, 128, 1.f / 262144.f);
    k3_gemm<<<dim3(4, 256, 4), 256, 0, stream>>>(h2, W3T, s2, t2, h3);
    kstats<<<256, 256, 0, stream>>>(h3, sum3, sumsq3, 64);
    kbnparam<<<1, 64, 0, stream>>>(sum3, sumsq3, g3, be3, s3, t3, 64, 1.f / 262144.f);
    k4_final<<<dim3(256, 4), 256, 0, stream>>>(h3, W4, s3, t3, b4, out);
}

// Round 4
// 264.484 us; speedup vs baseline: 1.7738x; 1.7738x over previous
//
#include <hip/hip_runtime.h>
#include <hip/hip_bf16.h>

#define EPS 1e-5f

typedef __attribute__((ext_vector_type(8))) short bf16x8;
typedef __attribute__((ext_vector_type(4))) float f32x4;

// ---------------- workspace layout (bytes) ----------------
static constexpr size_t OFF_FT    = 0;             // fT[b][c][n] f32 (1 MB)
static constexpr size_t OFF_W1T   = 1048576;       // W1T[c][o512] f32 (512 KB)
static constexpr size_t OFF_W2B   = 1572864;       // W2 bf16 [128][256] (64 KB)
static constexpr size_t OFF_W3B   = 1638400;       // W3 bf16 [64][128] (16 KB)
static constexpr size_t OFF_S1    = 1654784;
static constexpr size_t OFF_T1    = 1655808;
static constexpr size_t OFF_STATS = 1656832;       // sum2[128],sumsq2[128],sum3[64],sumsq3[64]
static constexpr size_t OFF_S2    = 1658368;
static constexpr size_t OFF_T2    = 1658880;
static constexpr size_t OFF_S3    = 1659392;
static constexpr size_t OFF_T3    = 1659648;
static constexpr size_t OFF_ABT   = 1703936;       // abT[b][n][o512] f32 (2 MB)
static constexpr size_t OFF_H2T   = 4194304;       // h2T[b][i][j][128] bf16 (64 MB)
static constexpr size_t OFF_H3T   = 71303168;      // h3T[b][i][j][64] bf16 (32 MB)
// end = 104857600 (100 MB, same footprint as round 2)

static __device__ inline float bfu2f(unsigned int u16) {
    return __uint_as_float(u16 << 16);
}
static __device__ inline unsigned short f2bfu(float f) {
    unsigned int u = __float_as_uint(f);
    unsigned int r = u + 0x7fffu + ((u >> 16) & 1u);   // RNE
    return (unsigned short)(r >> 16);
}

static __device__ inline float blockReduce256(float v, float* sred) {
    #pragma unroll
    for (int off = 32; off > 0; off >>= 1) v += __shfl_down(v, off);
    int lane = threadIdx.x & 63, w = threadIdx.x >> 6;
    __syncthreads();
    if (lane == 0) sred[w] = v;
    __syncthreads();
    return sred[0] + sred[1] + sred[2] + sred[3];
}

// ---------------- K0: pair-mean + transpose -> fT[b][c][n] ----------------
__global__ void k0_pairmean_T(const float* __restrict__ feats, float* __restrict__ fT) {
    __shared__ float s[64][65];
    int b = blockIdx.x >> 2;
    int n0 = (blockIdx.x & 3) * 64;
    int tid = threadIdx.x;
    const float* fb = feats + (size_t)b * 513 * 256;
    for (int c0 = 0; c0 < 256; c0 += 64) {
        for (int idx = tid; idx < 64 * 64; idx += 256) {
            int n = idx >> 6, c = idx & 63;
            const float* r = fb + (size_t)(1 + 2 * (n0 + n)) * 256 + c0 + c;
            s[n][c] = 0.5f * (r[0] + r[256]);
        }
        __syncthreads();
        for (int idx = tid; idx < 64 * 64; idx += 256) {
            int c = idx >> 6, n = idx & 63;
            fT[((size_t)b * 256 + c0 + c) * 256 + n0 + n] = s[n][c];
        }
        __syncthreads();
    }
}

// ---------------- kt_prep: W1 transpose (f32) + W2/W3 bf16 cast ----------------
__global__ void kt_prep(const float* __restrict__ W1, const float* __restrict__ W2,
                        const float* __restrict__ W3, float* __restrict__ W1T,
                        unsigned short* __restrict__ W2b, unsigned short* __restrict__ W3b) {
    int idx = blockIdx.x * 256 + threadIdx.x;
    if (idx < 131072) {
        int c = idx >> 9, o = idx & 511;
        W1T[idx] = (o < 256) ? W1[(size_t)o * 512 + c] : W1[(size_t)(o - 256) * 512 + 256 + c];
    } else if (idx < 163840) {
        int j = idx - 131072;
        W2b[j] = f2bfu(W2[j]);
    } else if (idx < 172032) {
        int j = idx - 163840;
        W3b[j] = f2bfu(W3[j]);
    }
}

// ---------------- K1: abT[b][n][o512] = sum_c W1T[c][o] * fT[b][c][n] ----------------
__global__ __launch_bounds__(256) void k1_gemm(const float* __restrict__ W1T,
                                               const float* __restrict__ fT,
                                               float* __restrict__ abT) {
    __shared__ float sW[64][68];
    __shared__ float sF[64][68];
    int tid = threadIdx.x;
    int b = blockIdx.x >> 2, n0 = (blockIdx.x & 3) * 64;
    int o0 = blockIdx.y * 64;
    int jq = tid & 15, og = tid >> 4;
    float acc[4][4] = {};
    for (int c0 = 0; c0 < 256; c0 += 64) {
        for (int idx = tid; idx < 64 * 64; idx += 256) {
            int c = idx >> 6, o = idx & 63;
            sW[c][o] = W1T[(size_t)(c0 + c) * 512 + o0 + o];
        }
        for (int idx = tid; idx < 64 * 64; idx += 256) {
            int c = idx >> 6, n = idx & 63;
            sF[c][n] = fT[((size_t)b * 256 + c0 + c) * 256 + n0 + n];
        }
        __syncthreads();
        #pragma unroll 8
        for (int c = 0; c < 64; ++c) {
            float4 rv = *(const float4*)&sF[c][jq * 4];
            float4 wv = *(const float4*)&sW[c][og * 4];
            float rr[4] = {rv.x, rv.y, rv.z, rv.w};
            float ww[4] = {wv.x, wv.y, wv.z, wv.w};
            #pragma unroll
            for (int m = 0; m < 4; ++m)
                #pragma unroll
                for (int w = 0; w < 4; ++w) acc[m][w] += ww[m] * rr[w];
        }
        __syncthreads();
    }
    // write channel-last: abT[b][n][o]; float4 over o (m-dir)
    for (int w = 0; w < 4; ++w) {
        int n = n0 + jq * 4 + w;
        float4 v = {acc[0][w], acc[1][w], acc[2][w], acc[3][w]};
        *(float4*)&abT[((size_t)(b * 256) + n) * 512 + o0 + og * 4] = v;
    }
}

// ---------------- K1b: analytic BN1 stats (reads abT columns, L2-resident) ----------------
__global__ void k1b_stats(const float* __restrict__ abT, const float* __restrict__ g1,
                          const float* __restrict__ be1, float* __restrict__ s1,
                          float* __restrict__ t1) {
    __shared__ float sred[4];
    int c = blockIdx.x, tid = threadIdx.x;
    float msum = 0.f, e2sum = 0.f;
    for (int b = 0; b < 4; ++b) {
        float va = abT[((size_t)(b * 256) + tid) * 512 + c];
        float vb = abT[((size_t)(b * 256) + tid) * 512 + 256 + c];
        float Sa = blockReduce256(va, sred);
        float Qa = blockReduce256(va * va, sred);
        float Sb = blockReduce256(vb, sred);
        float Qb = blockReduce256(vb * vb, sred);
        float ma = Sa * (1.f / 256.f), mb = Sb * (1.f / 256.f);
        msum += ma + mb;
        e2sum += Qa * (1.f / 256.f) + Qb * (1.f / 256.f) + 2.f * ma * mb;
    }
    if (tid == 0) {
        float m = msum * 0.25f, e2 = e2sum * 0.25f;
        float var = e2 - m * m;
        float s = g1[c] * rsqrtf(var + EPS);
        s1[c] = s;
        t1[c] = be1[c] - m * s;
    }
}

// ---------------- K2: h2T[b][i][j][o128] = W2 @ relu(bn1(a_i + bp_j)), MFMA ----------------
// grid (2 j-tiles, 256 i, 4 b), 256 thr = 4 waves (2x2), block tile 128o x 128j, K=256
__global__ __launch_bounds__(256) void k2_mfma(const float* __restrict__ abT,
                                               const unsigned short* __restrict__ W2b,
                                               const float* __restrict__ s1,
                                               const float* __restrict__ t1,
                                               unsigned short* __restrict__ h2T) {
    __shared__ __align__(16) char smem[34816];
    float* aaS = (float*)smem;                                    // [256]
    float* ssS = (float*)(smem + 1024);                           // [256]
    unsigned short* sW = (unsigned short*)(smem + 2048);          // [128][40]
    unsigned short* sB = (unsigned short*)(smem + 12288);         // [128][40]
    unsigned short* sT = (unsigned short*)smem;                   // [128][136] epilogue (overlaps)

    int tid = threadIdx.x;
    int j0 = blockIdx.x * 128, i = blockIdx.y, b = blockIdx.z;

    {
        float av = abT[((size_t)(b * 256 + i)) * 512 + tid];
        float s = s1[tid];
        aaS[tid] = fmaf(av, s, t1[tid]);
        ssS[tid] = s;
    }
    __syncthreads();

    int lane = tid & 63, wv = tid >> 6;
    int wr = wv >> 1, wc = wv & 1;
    int lo = lane & 15, khi = lane >> 4;

    f32x4 acc[4][4] = {};

    int jrow = tid >> 1, half = tid & 1;
    const float* bpRow = abT + ((size_t)(b * 256 + j0 + jrow)) * 512 + 256 + half * 16;
    const unsigned short* wRow = W2b + jrow * 256 + half * 16;
    int cb0 = half * 16;

    for (int c0 = 0; c0 < 256; c0 += 32) {
        // stage sW[o][c-chunk]
        {
            uint4 v0 = *(const uint4*)(wRow + c0);
            uint4 v1 = *(const uint4*)(wRow + c0 + 8);
            uint4* dst = (uint4*)(sW + jrow * 40 + half * 16);
            dst[0] = v0; dst[1] = v1;
        }
        // stage sB[j][c-chunk] = relu(aa[c] + bp*ss[c]) as bf16
        {
            float4 f0 = *(const float4*)(bpRow + c0);
            float4 f1 = *(const float4*)(bpRow + c0 + 4);
            float4 f2 = *(const float4*)(bpRow + c0 + 8);
            float4 f3 = *(const float4*)(bpRow + c0 + 12);
            float vv[16] = {f0.x,f0.y,f0.z,f0.w, f1.x,f1.y,f1.z,f1.w,
                            f2.x,f2.y,f2.z,f2.w, f3.x,f3.y,f3.z,f3.w};
            int cb = c0 + cb0;
            unsigned int u[8];
            #pragma unroll
            for (int e = 0; e < 8; ++e) {
                int c = cb + 2 * e;
                float r0 = fmaxf(fmaf(vv[2 * e],     ssS[c],     aaS[c]),     0.f);
                float r1 = fmaxf(fmaf(vv[2 * e + 1], ssS[c + 1], aaS[c + 1]), 0.f);
                u[e] = (unsigned int)f2bfu(r0) | ((unsigned int)f2bfu(r1) << 16);
            }
            uint4* dst = (uint4*)(sB + jrow * 40 + half * 16);
            dst[0] = make_uint4(u[0], u[1], u[2], u[3]);
            dst[1] = make_uint4(u[4], u[5], u[6], u[7]);
        }
        __syncthreads();
        const unsigned short* aBase = sW + (wr * 64 + lo) * 40 + khi * 8;
        const unsigned short* bBase = sB + (wc * 64 + lo) * 40 + khi * 8;
        bf16x8 af[4], bfr[4];
        #pragma unroll
        for (int fm = 0; fm < 4; ++fm) af[fm] = *(const bf16x8*)(aBase + fm * 16 * 40);
        #pragma unroll
        for (int fn = 0; fn < 4; ++fn) bfr[fn] = *(const bf16x8*)(bBase + fn * 16 * 40);
        #pragma unroll
        for (int fm = 0; fm < 4; ++fm)
            #pragma unroll
            for (int fn = 0; fn < 4; ++fn)
                acc[fm][fn] = __builtin_amdgcn_mfma_f32_16x16x32_bf16(af[fm], bfr[fn], acc[fm][fn], 0, 0, 0);
        __syncthreads();
    }

    // epilogue: LDS transpose to channel-last rows
    #pragma unroll
    for (int fm = 0; fm < 4; ++fm)
        #pragma unroll
        for (int fn = 0; fn < 4; ++fn) {
            int oq = wr * 64 + fm * 16 + khi * 4;
            int j  = wc * 64 + fn * 16 + lo;
            ushort4 pk;
            pk.x = f2bfu(acc[fm][fn][0]); pk.y = f2bfu(acc[fm][fn][1]);
            pk.z = f2bfu(acc[fm][fn][2]); pk.w = f2bfu(acc[fm][fn][3]);
            *(ushort4*)(sT + j * 136 + oq) = pk;
        }
    __syncthreads();
    size_t gbase = (((size_t)(b * 256 + i)) * 256 + j0 + jrow) * 128 + half * 64;
    #pragma unroll
    for (int e = 0; e < 8; ++e) {
        uint4 v = *(const uint4*)(sT + jrow * 136 + half * 64 + e * 8);
        *(uint4*)(h2T + gbase + e * 8) = v;
    }
}

// ---------------- kstatsT: per-channel sums over channel-last bf16 ----------------
__global__ void kstatsT(const unsigned short* __restrict__ h, float* __restrict__ sum,
                        float* __restrict__ sumsq, int C, int rowsPerBlock) {
    __shared__ float red[256][8];
    int tid = threadIdx.x;
    int G = C >> 3;
    int g = tid & (G - 1);
    int rl = tid / G;
    int rstep = 256 / G;
    float s[8] = {}, q[8] = {};
    size_t r0 = (size_t)blockIdx.x * rowsPerBlock;
    for (int r = rl; r < rowsPerBlock; r += rstep) {
        const unsigned short* p = h + (r0 + r) * C + g * 8;
        uint4 v = *(const uint4*)p;
        unsigned int w[4] = {v.x, v.y, v.z, v.w};
        #pragma unroll
        for (int k = 0; k < 4; ++k) {
            float f0 = bfu2f(w[k] & 0xffffu);
            float f1 = bfu2f(w[k] >> 16);
            s[2 * k] += f0; q[2 * k] += f0 * f0;
            s[2 * k + 1] += f1; q[2 * k + 1] += f1 * f1;
        }
    }
    #pragma unroll
    for (int e = 0; e < 8; ++e) red[tid][e] = s[e];
    __syncthreads();
    if (tid < C) {
        int gg = tid >> 3, e = tid & 7;
        float a = 0.f;
        for (int m = 0; m < rstep; ++m) a += red[gg + m * G][e];
        atomicAdd(&sum[tid], a);
    }
    __syncthreads();
    #pragma unroll
    for (int e = 0; e < 8; ++e) red[tid][e] = q[e];
    __syncthreads();
    if (tid < C) {
        int gg = tid >> 3, e = tid & 7;
        float a = 0.f;
        for (int m = 0; m < rstep; ++m) a += red[gg + m * G][e];
        atomicAdd(&sumsq[tid], a);
    }
}

__global__ void kbnparam(const float* __restrict__ sum, const float* __restrict__ sumsq,
                         const float* __restrict__ g, const float* __restrict__ be,
                         float* __restrict__ s, float* __restrict__ t, int C, float invc) {
    int o = threadIdx.x;
    if (o < C) {
        float mean = sum[o] * invc;
        float var = sumsq[o] * invc - mean * mean;
        float sc = g[o] * rsqrtf(var + EPS);
        s[o] = sc;
        t[o] = be[o] - mean * sc;
    }
}

// ---------------- K3: h3T = W3 @ relu(bn2(h2T)), MFMA ----------------
// grid (256 i, 4 b), 256 thr = 4 waves (1x4), block tile 64o x 256j, K=128
__global__ __launch_bounds__(256) void k3_mfma(const unsigned short* __restrict__ h2T,
                                               const unsigned short* __restrict__ W3b,
                                               const float* __restrict__ s2,
                                               const float* __restrict__ t2,
                                               unsigned short* __restrict__ h3T) {
    __shared__ __align__(16) char smem[38912];
    float* s2S = (float*)smem;                                    // [128]
    float* t2S = (float*)(smem + 512);                            // [128]
    unsigned short* sW3 = (unsigned short*)(smem + 1024);         // [64][136] full K
    unsigned short* sB  = (unsigned short*)(smem + 18432);        // [256][40] chunk
    unsigned short* sT  = (unsigned short*)(smem + 1024);         // [256][72] epilogue (overlaps)

    int tid = threadIdx.x;
    int i = blockIdx.x, b = blockIdx.y;
    if (tid < 128) { s2S[tid] = s2[tid]; t2S[tid] = t2[tid]; }
    {
        int o = tid >> 2, qd = tid & 3;
        #pragma unroll
        for (int e = 0; e < 4; ++e) {
            uint4 v = *(const uint4*)(W3b + o * 128 + qd * 32 + e * 8);
            *(uint4*)(sW3 + o * 136 + qd * 32 + e * 8) = v;
        }
    }
    __syncthreads();

    int lane = tid & 63, wv = tid >> 6;
    int lo = lane & 15, khi = lane >> 4;

    f32x4 acc[4][4] = {};
    const unsigned short* src = h2T + (((size_t)(b * 256 + i)) * 256 + tid) * 128;

    for (int c0 = 0; c0 < 128; c0 += 32) {
        // stage sB[j=tid][c-chunk] = relu(bn2(h2)) bf16
        #pragma unroll
        for (int e = 0; e < 4; ++e) {
            uint4 v = *(const uint4*)(src + c0 + e * 8);
            unsigned int w[4] = {v.x, v.y, v.z, v.w};
            unsigned int ou[4];
            #pragma unroll
            for (int k = 0; k < 4; ++k) {
                int c = c0 + e * 8 + 2 * k;
                float f0 = bfu2f(w[k] & 0xffffu);
                float f1 = bfu2f(w[k] >> 16);
                float r0 = fmaxf(fmaf(f0, s2S[c],     t2S[c]),     0.f);
                float r1 = fmaxf(fmaf(f1, s2S[c + 1], t2S[c + 1]), 0.f);
                ou[k] = (unsigned int)f2bfu(r0) | ((unsigned int)f2bfu(r1) << 16);
            }
            *(uint4*)(sB + tid * 40 + e * 8) = make_uint4(ou[0], ou[1], ou[2], ou[3]);
        }
        __syncthreads();
        bf16x8 af[4], bfr[4];
        #pragma unroll
        for (int fm = 0; fm < 4; ++fm)
            af[fm] = *(const bf16x8*)(sW3 + (fm * 16 + lo) * 136 + c0 + khi * 8);
        #pragma unroll
        for (int fn = 0; fn < 4; ++fn)
            bfr[fn] = *(const bf16x8*)(sB + (wv * 64 + fn * 16 + lo) * 40 + khi * 8);
        #pragma unroll
        for (int fm = 0; fm < 4; ++fm)
            #pragma unroll
            for (int fn = 0; fn < 4; ++fn)
                acc[fm][fn] = __builtin_amdgcn_mfma_f32_16x16x32_bf16(af[fm], bfr[fn], acc[fm][fn], 0, 0, 0);
        __syncthreads();
    }

    // epilogue: transpose to channel-last
    #pragma unroll
    for (int fm = 0; fm < 4; ++fm)
        #pragma unroll
        for (int fn = 0; fn < 4; ++fn) {
            int oq = fm * 16 + khi * 4;
            int j  = wv * 64 + fn * 16 + lo;
            ushort4 pk;
            pk.x = f2bfu(acc[fm][fn][0]); pk.y = f2bfu(acc[fm][fn][1]);
            pk.z = f2bfu(acc[fm][fn][2]); pk.w = f2bfu(acc[fm][fn][3]);
            *(ushort4*)(sT + j * 72 + oq) = pk;
        }
    __syncthreads();
    size_t gbase = (((size_t)(b * 256 + i)) * 256 + tid) * 64;
    #pragma unroll
    for (int e = 0; e < 8; ++e) {
        uint4 v = *(const uint4*)(sT + tid * 72 + e * 8);
        *(uint4*)(h3T + gbase + e * 8) = v;
    }
}

// ---------------- K4: out = W4 @ relu(bn3(h3T)) + b4 ----------------
__global__ __launch_bounds__(256) void k4_final(const unsigned short* __restrict__ h3T,
                                                const float* __restrict__ W4,
                                                const float* __restrict__ s3,
                                                const float* __restrict__ t3,
                                                const float* __restrict__ b4,
                                                float* __restrict__ out) {
    __shared__ __align__(16) char smem[37632];
    float* wS = (float*)smem;            // [64]
    float* sS = (float*)(smem + 256);    // [64]
    float* tS = (float*)(smem + 512);    // [64]
    unsigned short* sL = (unsigned short*)(smem + 768);  // [256][72]
    int tid = threadIdx.x;
    int i = blockIdx.x, b = blockIdx.y;
    if (tid < 64) { wS[tid] = W4[tid]; sS[tid] = s3[tid]; tS[tid] = t3[tid]; }
    const unsigned short* src = h3T + ((size_t)(b * 256 + i)) * 256 * 64;
    #pragma unroll
    for (int e = 0; e < 8; ++e) {
        int f = tid + 256 * e;           // uint4 index; row j = f>>3, seg = f&7
        uint4 v = *(const uint4*)(src + f * 8);
        *(uint4*)(sL + (f >> 3) * 72 + (f & 7) * 8) = v;
    }
    __syncthreads();
    float acc = 0.f;
    #pragma unroll
    for (int e = 0; e < 8; ++e) {
        uint4 v = *(const uint4*)(sL + tid * 72 + e * 8);
        unsigned int w[4] = {v.x, v.y, v.z, v.w};
        #pragma unroll
        for (int k = 0; k < 4; ++k) {
            int c = e * 8 + 2 * k;
            float f0 = bfu2f(w[k] & 0xffffu);
            float f1 = bfu2f(w[k] >> 16);
            acc += wS[c] * fmaxf(fmaf(f0, sS[c], tS[c]), 0.f);
            acc += wS[c + 1] * fmaxf(fmaf(f1, sS[c + 1], tS[c + 1]), 0.f);
        }
    }
    out[((size_t)(b * 256 + i)) * 256 + tid] = acc + b4[0];
}

extern "C" void kernel_launch(void* const* d_in, const int* in_sizes, int n_in,
                              void* d_out, int out_size, void* d_ws, size_t ws_size,
                              hipStream_t stream) {
    const float* feats = (const float*)d_in[0];
    const float* W1  = (const float*)d_in[1];
    const float* g1  = (const float*)d_in[3];
    const float* be1 = (const float*)d_in[4];
    const float* W2  = (const float*)d_in[5];
    const float* g2  = (const float*)d_in[7];
    const float* be2 = (const float*)d_in[8];
    const float* W3  = (const float*)d_in[9];
    const float* g3  = (const float*)d_in[11];
    const float* be3 = (const float*)d_in[12];
    const float* W4  = (const float*)d_in[13];
    const float* b4  = (const float*)d_in[14];

    char* ws = (char*)d_ws;
    float* fT   = (float*)(ws + OFF_FT);
    float* W1T  = (float*)(ws + OFF_W1T);
    unsigned short* W2b = (unsigned short*)(ws + OFF_W2B);
    unsigned short* W3b = (unsigned short*)(ws + OFF_W3B);
    float* abT  = (float*)(ws + OFF_ABT);
    float* s1   = (float*)(ws + OFF_S1);
    float* t1   = (float*)(ws + OFF_T1);
    float* sum2   = (float*)(ws + OFF_STATS);
    float* sumsq2 = (float*)(ws + OFF_STATS + 512);
    float* sum3   = (float*)(ws + OFF_STATS + 1024);
    float* sumsq3 = (float*)(ws + OFF_STATS + 1280);
    float* s2 = (float*)(ws + OFF_S2);
    float* t2 = (float*)(ws + OFF_T2);
    float* s3 = (float*)(ws + OFF_S3);
    float* t3 = (float*)(ws + OFF_T3);
    unsigned short* h2T = (unsigned short*)(ws + OFF_H2T);
    unsigned short* h3T = (unsigned short*)(ws + OFF_H3T);
    float* out = (float*)d_out;

    hipMemsetAsync(ws + OFF_STATS, 0, 1536, stream);

    k0_pairmean_T<<<16, 256, 0, stream>>>(feats, fT);
    kt_prep<<<672, 256, 0, stream>>>(W1, W2, W3, W1T, W2b, W3b);
    k1_gemm<<<dim3(16, 8), 256, 0, stream>>>(W1T, fT, abT);
    k1b_stats<<<256, 256, 0, stream>>>(abT, g1, be1, s1, t1);
    k2_mfma<<<dim3(2, 256, 4), 256, 0, stream>>>(abT, W2b, s1, t1, h2T);
    kstatsT<<<512, 256, 0, stream>>>(h2T, sum2, sumsq2, 128, 512);
    kbnparam<<<1, 128, 0, stream>>>(sum2, sumsq2, g2, be2, s2, t2, 128, 1.f / 262144.f);
    k3_mfma<<<dim3(256, 4), 256, 0, stream>>>(h2T, W3b, s2, t2, h3T);
    kstatsT<<<512, 256, 0, stream>>>(h3T, sum3, sumsq3, 64, 512);
    kbnparam<<<1, 64, 0, stream>>>(sum3, sumsq3, g3, be3, s3, t3, 64, 1.f / 262144.f);
    k4_final<<<dim3(256, 4), 256, 0, stream>>>(h3T, W4, s3, t3, b4, out);
}

// Round 5
// 241.586 us; speedup vs baseline: 1.9419x; 1.0948x over previous
//
#include <hip/hip_runtime.h>
#include <hip/hip_bf16.h>

#define EPS 1e-5f

typedef __attribute__((ext_vector_type(8))) short bf16x8;
typedef __attribute__((ext_vector_type(4))) float f32x4;

// ---------------- workspace layout (bytes) ----------------
static constexpr size_t OFF_FT    = 0;             // fT[b][c][n] f32 (1 MB)
static constexpr size_t OFF_W1T   = 1048576;       // W1T[c][o512] f32 (512 KB)
static constexpr size_t OFF_W2B   = 1572864;       // W2 bf16 [128][256] (64 KB)
static constexpr size_t OFF_W3B   = 1638400;       // W3 bf16 [64][128] (16 KB)
static constexpr size_t OFF_S1    = 1654784;
static constexpr size_t OFF_T1    = 1655808;
static constexpr size_t OFF_S2    = 1658368;
static constexpr size_t OFF_T2    = 1658880;
static constexpr size_t OFF_S3    = 1659392;
static constexpr size_t OFF_T3    = 1659648;
static constexpr size_t OFF_ST2   = 1660928;       // gS2[8][128], gQ2[8][128] (8 KB, memset 0)
static constexpr size_t OFF_ST3   = 1669120;       // gS3[8][64], gQ3[8][64] (4 KB, memset 0)
static constexpr size_t OFF_ABT   = 1703936;       // abT[b][n][o512] f32 (2 MB)
static constexpr size_t OFF_H2T   = 4194304;       // h2T bf16 (64 MB); k1 partials overlap (dead before k2)
static constexpr size_t OFF_P1    = OFF_H2T;       // part float2[16][512] (64 KB), k1->k1b only
static constexpr size_t OFF_H3T   = 71303168;      // h3T bf16 (32 MB)

static __device__ inline float bfu2f(unsigned int u16) {
    return __uint_as_float(u16 << 16);
}
static __device__ inline unsigned short f2bfu(float f) {
    unsigned int u = __float_as_uint(f);
    unsigned int r = u + 0x7fffu + ((u >> 16) & 1u);   // RNE
    return (unsigned short)(r >> 16);
}
static __device__ inline unsigned int pkbf(float lo, float hi) {
    __hip_bfloat162 p = __float22bfloat162_rn(make_float2(lo, hi));   // v_cvt_pk_bf16_f32
    return *reinterpret_cast<unsigned int*>(&p);
}

// ---------------- K0: pair-mean + transpose -> fT[b][c][n] ----------------
__global__ void k0_pairmean_T(const float* __restrict__ feats, float* __restrict__ fT) {
    __shared__ float s[64][65];
    int b = blockIdx.x >> 2;
    int n0 = (blockIdx.x & 3) * 64;
    int tid = threadIdx.x;
    const float* fb = feats + (size_t)b * 513 * 256;
    for (int c0 = 0; c0 < 256; c0 += 64) {
        for (int idx = tid; idx < 64 * 64; idx += 256) {
            int n = idx >> 6, c = idx & 63;
            const float* r = fb + (size_t)(1 + 2 * (n0 + n)) * 256 + c0 + c;
            s[n][c] = 0.5f * (r[0] + r[256]);
        }
        __syncthreads();
        for (int idx = tid; idx < 64 * 64; idx += 256) {
            int c = idx >> 6, n = idx & 63;
            fT[((size_t)b * 256 + c0 + c) * 256 + n0 + n] = s[n][c];
        }
        __syncthreads();
    }
}

// ---------------- kt_prep: W1 transpose (f32) + W2/W3 bf16 cast ----------------
__global__ void kt_prep(const float* __restrict__ W1, const float* __restrict__ W2,
                        const float* __restrict__ W3, float* __restrict__ W1T,
                        unsigned short* __restrict__ W2b, unsigned short* __restrict__ W3b) {
    int idx = blockIdx.x * 256 + threadIdx.x;
    if (idx < 131072) {
        int c = idx >> 9, o = idx & 511;
        W1T[idx] = (o < 256) ? W1[(size_t)o * 512 + c] : W1[(size_t)(o - 256) * 512 + 256 + c];
    } else if (idx < 163840) {
        int j = idx - 131072;
        W2b[j] = f2bfu(W2[j]);
    } else if (idx < 172032) {
        int j = idx - 163840;
        W3b[j] = f2bfu(W3[j]);
    }
}

// ---------------- K1: abT[b][n][o512] = sum_c W1T[c][o] * fT[b][c][n] + BN1 partials ----------------
__global__ __launch_bounds__(256) void k1_gemm(const float* __restrict__ W1T,
                                               const float* __restrict__ fT,
                                               float* __restrict__ abT,
                                               float2* __restrict__ part) {
    __shared__ float sW[64][68];
    __shared__ float sF[64][68];
    int tid = threadIdx.x;
    int b = blockIdx.x >> 2, n0 = (blockIdx.x & 3) * 64;
    int o0 = blockIdx.y * 64;
    int jq = tid & 15, og = tid >> 4;
    float acc[4][4] = {};
    for (int c0 = 0; c0 < 256; c0 += 64) {
        for (int idx = tid; idx < 64 * 64; idx += 256) {
            int c = idx >> 6, o = idx & 63;
            sW[c][o] = W1T[(size_t)(c0 + c) * 512 + o0 + o];
        }
        for (int idx = tid; idx < 64 * 64; idx += 256) {
            int c = idx >> 6, n = idx & 63;
            sF[c][n] = fT[((size_t)b * 256 + c0 + c) * 256 + n0 + n];
        }
        __syncthreads();
        #pragma unroll 8
        for (int c = 0; c < 64; ++c) {
            float4 rv = *(const float4*)&sF[c][jq * 4];
            float4 wv = *(const float4*)&sW[c][og * 4];
            float rr[4] = {rv.x, rv.y, rv.z, rv.w};
            float ww[4] = {wv.x, wv.y, wv.z, wv.w};
            #pragma unroll
            for (int m = 0; m < 4; ++m)
                #pragma unroll
                for (int w = 0; w < 4; ++w) acc[m][w] += ww[m] * rr[w];
        }
        __syncthreads();
    }
    // write channel-last: abT[b][n][o]
    for (int w = 0; w < 4; ++w) {
        int n = n0 + jq * 4 + w;
        float4 v = {acc[0][w], acc[1][w], acc[2][w], acc[3][w]};
        *(float4*)&abT[((size_t)(b * 256) + n) * 512 + o0 + og * 4] = v;
    }
    // BN1 partials: per-o sum/sumsq over this block's 64 n's
    #pragma unroll
    for (int m = 0; m < 4; ++m) {
        float s = 0.f, q = 0.f;
        #pragma unroll
        for (int w = 0; w < 4; ++w) { float v = acc[m][w]; s += v; q += v * v; }
        #pragma unroll
        for (int off = 8; off; off >>= 1) { s += __shfl_down(s, off); q += __shfl_down(q, off); }
        if (jq == 0) part[(size_t)blockIdx.x * 512 + o0 + og * 4 + m] = make_float2(s, q);
    }
}

// ---------------- K1b: tiny BN1 param solve from partials ----------------
__global__ void k1b_stats(const float2* __restrict__ part, const float* __restrict__ g1,
                          const float* __restrict__ be1, float* __restrict__ s1,
                          float* __restrict__ t1) {
    __shared__ float Sl[4][512], Ql[4][512];
    int o = threadIdx.x;
    for (int b = 0; b < 4; ++b) {
        float s = 0.f, q = 0.f;
        #pragma unroll
        for (int nt = 0; nt < 4; ++nt) {
            float2 p = part[(size_t)(b * 4 + nt) * 512 + o];
            s += p.x; q += p.y;
        }
        Sl[b][o] = s; Ql[b][o] = q;
    }
    __syncthreads();
    if (o < 256) {
        float msum = 0.f, e2sum = 0.f;
        #pragma unroll
        for (int b = 0; b < 4; ++b) {
            float ma = Sl[b][o] * (1.f / 256.f), mb = Sl[b][o + 256] * (1.f / 256.f);
            msum += ma + mb;
            e2sum += Ql[b][o] * (1.f / 256.f) + Ql[b][o + 256] * (1.f / 256.f) + 2.f * ma * mb;
        }
        float m = msum * 0.25f, e2 = e2sum * 0.25f;
        float var = e2 - m * m;
        float s = g1[o] * rsqrtf(var + EPS);
        s1[o] = s;
        t1[o] = be1[o] - m * s;
    }
}

// ---------------- K2: h2T = W2 @ relu(bn1(a_i + bp_j)), MFMA, BK=64, fused stats ----------------
// grid (2 j-tiles, 256 i, 4 b), 256 thr = 4 waves (2x2), block tile 128o x 128j, K=256
__global__ __launch_bounds__(256) void k2_mfma(const float* __restrict__ abT,
                                               const unsigned short* __restrict__ W2b,
                                               const float* __restrict__ s1,
                                               const float* __restrict__ t1,
                                               unsigned short* __restrict__ h2T,
                                               float* __restrict__ gS2,
                                               float* __restrict__ gQ2) {
    __shared__ __align__(16) char smem[39936];
    float* aaS = (float*)smem;                                    // [256] 1KB
    float* ssS = (float*)(smem + 1024);                           // [256] 1KB
    unsigned short* sW = (unsigned short*)(smem + 2048);          // [128][72] 18432
    unsigned short* sB = (unsigned short*)(smem + 20480);         // [128][72] 18432
    float* sS = (float*)(smem + 38912);                           // [128]
    float* sQ = (float*)(smem + 39424);                           // [128]
    unsigned short* sT = (unsigned short*)smem;                   // [128][136] epilogue (overlaps aa/sW/sB)

    int tid = threadIdx.x;
    int j0 = blockIdx.x * 128, i = blockIdx.y, b = blockIdx.z;

    {
        float av = abT[((size_t)(b * 256 + i)) * 512 + tid];
        float s = s1[tid];
        aaS[tid] = fmaf(av, s, t1[tid]);
        ssS[tid] = s;
    }
    if (tid < 128) { sS[tid] = 0.f; sQ[tid] = 0.f; }
    __syncthreads();

    int lane = tid & 63, wv = tid >> 6;
    int wr = wv >> 1, wc = wv & 1;
    int lo = lane & 15, khi = lane >> 4;

    f32x4 acc[4][4] = {};
    const float* bpB = abT + ((size_t)(b * 256 + j0)) * 512 + 256;

    for (int c0 = 0; c0 < 256; c0 += 64) {
        // stage W tile [128 o][64 c]: 1024 uint4, coalesced
        #pragma unroll
        for (int k = 0; k < 4; ++k) {
            int f = tid + k * 256; int o = f >> 3, cs = f & 7;
            uint4 v = *(const uint4*)(W2b + o * 256 + c0 + cs * 8);
            *(uint4*)(sW + o * 72 + cs * 8) = v;
        }
        // stage B tile [128 j][64 c] = relu(aa + bp*ss) bf16: 2048 float4 units
        #pragma unroll
        for (int k = 0; k < 8; ++k) {
            int f = tid + k * 256; int j = f >> 4, cs = f & 15;
            float4 bp = *(const float4*)(bpB + (size_t)j * 512 + c0 + cs * 4);
            float4 a4 = *(const float4*)&aaS[c0 + cs * 4];
            float4 s4 = *(const float4*)&ssS[c0 + cs * 4];
            float r0 = fmaxf(fmaf(bp.x, s4.x, a4.x), 0.f);
            float r1 = fmaxf(fmaf(bp.y, s4.y, a4.y), 0.f);
            float r2 = fmaxf(fmaf(bp.z, s4.z, a4.z), 0.f);
            float r3 = fmaxf(fmaf(bp.w, s4.w, a4.w), 0.f);
            *(uint2*)(sB + j * 72 + cs * 4) = make_uint2(pkbf(r0, r1), pkbf(r2, r3));
        }
        __syncthreads();
        const unsigned short* aB = sW + (wr * 64 + lo) * 72 + khi * 8;
        const unsigned short* bB = sB + (wc * 64 + lo) * 72 + khi * 8;
        #pragma unroll
        for (int ks = 0; ks < 2; ++ks) {
            bf16x8 af[4], bfr[4];
            #pragma unroll
            for (int fm = 0; fm < 4; ++fm) af[fm] = *(const bf16x8*)(aB + fm * 16 * 72 + ks * 32);
            #pragma unroll
            for (int fn = 0; fn < 4; ++fn) bfr[fn] = *(const bf16x8*)(bB + fn * 16 * 72 + ks * 32);
            #pragma unroll
            for (int fm = 0; fm < 4; ++fm)
                #pragma unroll
                for (int fn = 0; fn < 4; ++fn)
                    acc[fm][fn] = __builtin_amdgcn_mfma_f32_16x16x32_bf16(af[fm], bfr[fn], acc[fm][fn], 0, 0, 0);
        }
        __syncthreads();
    }

    // fused BN2 stats: per-o sum/sumsq over this block's 128 j's (f32, pre-rounding)
    #pragma unroll
    for (int fm = 0; fm < 4; ++fm)
        #pragma unroll
        for (int r = 0; r < 4; ++r) {
            float s = 0.f, q = 0.f;
            #pragma unroll
            for (int fn = 0; fn < 4; ++fn) { float v = acc[fm][fn][r]; s += v; q += v * v; }
            #pragma unroll
            for (int off = 8; off; off >>= 1) { s += __shfl_down(s, off); q += __shfl_down(q, off); }
            if (lo == 0) {
                int o = wr * 64 + fm * 16 + khi * 4 + r;
                atomicAdd(&sS[o], s);
                atomicAdd(&sQ[o], q);
            }
        }
    __syncthreads();

    // epilogue: LDS transpose to channel-last rows
    #pragma unroll
    for (int fm = 0; fm < 4; ++fm)
        #pragma unroll
        for (int fn = 0; fn < 4; ++fn) {
            int oq = wr * 64 + fm * 16 + khi * 4;
            int j  = wc * 64 + fn * 16 + lo;
            unsigned int u0 = pkbf(acc[fm][fn][0], acc[fm][fn][1]);
            unsigned int u1 = pkbf(acc[fm][fn][2], acc[fm][fn][3]);
            *(uint2*)(sT + j * 136 + oq) = make_uint2(u0, u1);
        }
    __syncthreads();
    {
        int jrow = tid >> 1, half = tid & 1;
        size_t gbase = (((size_t)(b * 256 + i)) * 256 + j0 + jrow) * 128 + half * 64;
        #pragma unroll
        for (int e = 0; e < 8; ++e) {
            uint4 v = *(const uint4*)(sT + jrow * 136 + half * 64 + e * 8);
            *(uint4*)(h2T + gbase + e * 8) = v;
        }
    }
    if (tid < 128) {
        int slot = (i & 7) * 128;
        atomicAdd(&gS2[slot + tid], sS[tid]);
        atomicAdd(&gQ2[slot + tid], sQ[tid]);
    }
}

// ---------------- bn params from 8-shadow sums ----------------
__global__ void kbnparam(const float* __restrict__ gS, const float* __restrict__ gQ,
                         const float* __restrict__ g, const float* __restrict__ be,
                         float* __restrict__ s, float* __restrict__ t, int C, float invc) {
    int o = threadIdx.x;
    if (o < C) {
        float su = 0.f, qu = 0.f;
        #pragma unroll
        for (int k = 0; k < 8; ++k) { su += gS[k * C + o]; qu += gQ[k * C + o]; }
        float mean = su * invc;
        float var = qu * invc - mean * mean;
        float sc = g[o] * rsqrtf(var + EPS);
        s[o] = sc;
        t[o] = be[o] - mean * sc;
    }
}

// ---------------- K3: h3T = W3 @ relu(bn2(h2T)), MFMA, fused stats ----------------
// grid (256 i, 4 b), 256 thr = 4 waves (1x4), block tile 64o x 256j, K=128
__global__ __launch_bounds__(256) void k3_mfma(const unsigned short* __restrict__ h2T,
                                               const unsigned short* __restrict__ W3b,
                                               const float* __restrict__ s2,
                                               const float* __restrict__ t2,
                                               unsigned short* __restrict__ h3T,
                                               float* __restrict__ gS3,
                                               float* __restrict__ gQ3) {
    __shared__ __align__(16) char smem[39424];
    float* s2S = (float*)smem;                                    // [128]
    float* t2S = (float*)(smem + 512);                            // [128]
    unsigned short* sW3 = (unsigned short*)(smem + 1024);         // [64][136] full K
    unsigned short* sB  = (unsigned short*)(smem + 18432);        // [256][40] chunk
    float* sS = (float*)(smem + 38912);                           // [64]
    float* sQ = (float*)(smem + 39168);                           // [64]
    unsigned short* sT  = (unsigned short*)(smem + 1024);         // [256][72] epilogue (overlaps W3/sB)

    int tid = threadIdx.x;
    int i = blockIdx.x, b = blockIdx.y;
    if (tid < 128) { s2S[tid] = s2[tid]; t2S[tid] = t2[tid]; }
    if (tid < 64) { sS[tid] = 0.f; sQ[tid] = 0.f; }
    {
        int o = tid >> 2, qd = tid & 3;
        #pragma unroll
        for (int e = 0; e < 4; ++e) {
            uint4 v = *(const uint4*)(W3b + o * 128 + qd * 32 + e * 8);
            *(uint4*)(sW3 + o * 136 + qd * 32 + e * 8) = v;
        }
    }
    __syncthreads();

    int lane = tid & 63, wv = tid >> 6;
    int lo = lane & 15, khi = lane >> 4;

    f32x4 acc[4][4] = {};
    const unsigned short* src = h2T + (((size_t)(b * 256 + i)) * 256 + tid) * 128;

    for (int c0 = 0; c0 < 128; c0 += 32) {
        // stage sB[j=tid][c-chunk] = relu(bn2(h2)) bf16, vectorized
        #pragma unroll
        for (int e = 0; e < 4; ++e) {
            uint4 v = *(const uint4*)(src + c0 + e * 8);
            int c = c0 + e * 8;
            float4 sa = *(const float4*)&s2S[c];
            float4 sb = *(const float4*)&s2S[c + 4];
            float4 ta = *(const float4*)&t2S[c];
            float4 tb = *(const float4*)&t2S[c + 4];
            float r0 = fmaxf(fmaf(bfu2f(v.x & 0xffffu), sa.x, ta.x), 0.f);
            float r1 = fmaxf(fmaf(bfu2f(v.x >> 16),     sa.y, ta.y), 0.f);
            float r2 = fmaxf(fmaf(bfu2f(v.y & 0xffffu), sa.z, ta.z), 0.f);
            float r3 = fmaxf(fmaf(bfu2f(v.y >> 16),     sa.w, ta.w), 0.f);
            float r4 = fmaxf(fmaf(bfu2f(v.z & 0xffffu), sb.x, tb.x), 0.f);
            float r5 = fmaxf(fmaf(bfu2f(v.z >> 16),     sb.y, tb.y), 0.f);
            float r6 = fmaxf(fmaf(bfu2f(v.w & 0xffffu), sb.z, tb.z), 0.f);
            float r7 = fmaxf(fmaf(bfu2f(v.w >> 16),     sb.w, tb.w), 0.f);
            *(uint4*)(sB + tid * 40 + e * 8) =
                make_uint4(pkbf(r0, r1), pkbf(r2, r3), pkbf(r4, r5), pkbf(r6, r7));
        }
        __syncthreads();
        bf16x8 af[4], bfr[4];
        #pragma unroll
        for (int fm = 0; fm < 4; ++fm)
            af[fm] = *(const bf16x8*)(sW3 + (fm * 16 + lo) * 136 + c0 + khi * 8);
        #pragma unroll
        for (int fn = 0; fn < 4; ++fn)
            bfr[fn] = *(const bf16x8*)(sB + (wv * 64 + fn * 16 + lo) * 40 + khi * 8);
        #pragma unroll
        for (int fm = 0; fm < 4; ++fm)
            #pragma unroll
            for (int fn = 0; fn < 4; ++fn)
                acc[fm][fn] = __builtin_amdgcn_mfma_f32_16x16x32_bf16(af[fm], bfr[fn], acc[fm][fn], 0, 0, 0);
        __syncthreads();
    }

    // fused BN3 stats
    #pragma unroll
    for (int fm = 0; fm < 4; ++fm)
        #pragma unroll
        for (int r = 0; r < 4; ++r) {
            float s = 0.f, q = 0.f;
            #pragma unroll
            for (int fn = 0; fn < 4; ++fn) { float v = acc[fm][fn][r]; s += v; q += v * v; }
            #pragma unroll
            for (int off = 8; off; off >>= 1) { s += __shfl_down(s, off); q += __shfl_down(q, off); }
            if (lo == 0) {
                int o = fm * 16 + khi * 4 + r;
                atomicAdd(&sS[o], s);
                atomicAdd(&sQ[o], q);
            }
        }
    __syncthreads();

    // epilogue: transpose to channel-last
    #pragma unroll
    for (int fm = 0; fm < 4; ++fm)
        #pragma unroll
        for (int fn = 0; fn < 4; ++fn) {
            int oq = fm * 16 + khi * 4;
            int j  = wv * 64 + fn * 16 + lo;
            unsigned int u0 = pkbf(acc[fm][fn][0], acc[fm][fn][1]);
            unsigned int u1 = pkbf(acc[fm][fn][2], acc[fm][fn][3]);
            *(uint2*)(sT + j * 72 + oq) = make_uint2(u0, u1);
        }
    __syncthreads();
    {
        size_t gbase = (((size_t)(b * 256 + i)) * 256 + tid) * 64;
        #pragma unroll
        for (int e = 0; e < 8; ++e) {
            uint4 v = *(const uint4*)(sT + tid * 72 + e * 8);
            *(uint4*)(h3T + gbase + e * 8) = v;
        }
    }
    if (tid < 64) {
        int slot = (i & 7) * 64;
        atomicAdd(&gS3[slot + tid], sS[tid]);
        atomicAdd(&gQ3[slot + tid], sQ[tid]);
    }
}

// ---------------- K4: out = W4 @ relu(bn3(h3T)) + b4 ----------------
__global__ __launch_bounds__(256) void k4_final(const unsigned short* __restrict__ h3T,
                                                const float* __restrict__ W4,
                                                const float* __restrict__ s3,
                                                const float* __restrict__ t3,
                                                const float* __restrict__ b4,
                                                float* __restrict__ out) {
    __shared__ __align__(16) char smem[37632];
    float* wS = (float*)smem;            // [64]
    float* sS = (float*)(smem + 256);    // [64]
    float* tS = (float*)(smem + 512);    // [64]
    unsigned short* sL = (unsigned short*)(smem + 768);  // [256][72]
    int tid = threadIdx.x;
    int i = blockIdx.x, b = blockIdx.y;
    if (tid < 64) { wS[tid] = W4[tid]; sS[tid] = s3[tid]; tS[tid] = t3[tid]; }
    const unsigned short* src = h3T + ((size_t)(b * 256 + i)) * 256 * 64;
    #pragma unroll
    for (int e = 0; e < 8; ++e) {
        int f = tid + 256 * e;
        uint4 v = *(const uint4*)(src + f * 8);
        *(uint4*)(sL + (f >> 3) * 72 + (f & 7) * 8) = v;
    }
    __syncthreads();
    float acc = 0.f;
    #pragma unroll
    for (int e = 0; e < 8; ++e) {
        uint4 v = *(const uint4*)(sL + tid * 72 + e * 8);
        unsigned int w[4] = {v.x, v.y, v.z, v.w};
        #pragma unroll
        for (int k = 0; k < 4; ++k) {
            int c = e * 8 + 2 * k;
            float f0 = bfu2f(w[k] & 0xffffu);
            float f1 = bfu2f(w[k] >> 16);
            acc += wS[c] * fmaxf(fmaf(f0, sS[c], tS[c]), 0.f);
            acc += wS[c + 1] * fmaxf(fmaf(f1, sS[c + 1], tS[c + 1]), 0.f);
        }
    }
    out[((size_t)(b * 256 + i)) * 256 + tid] = acc + b4[0];
}

extern "C" void kernel_launch(void* const* d_in, const int* in_sizes, int n_in,
                              void* d_out, int out_size, void* d_ws, size_t ws_size,
                              hipStream_t stream) {
    const float* feats = (const float*)d_in[0];
    const float* W1  = (const float*)d_in[1];
    const float* g1  = (const float*)d_in[3];
    const float* be1 = (const float*)d_in[4];
    const float* W2  = (const float*)d_in[5];
    const float* g2  = (const float*)d_in[7];
    const float* be2 = (const float*)d_in[8];
    const float* W3  = (const float*)d_in[9];
    const float* g3  = (const float*)d_in[11];
    const float* be3 = (const float*)d_in[12];
    const float* W4  = (const float*)d_in[13];
    const float* b4  = (const float*)d_in[14];

    char* ws = (char*)d_ws;
    float* fT   = (float*)(ws + OFF_FT);
    float* W1T  = (float*)(ws + OFF_W1T);
    unsigned short* W2b = (unsigned short*)(ws + OFF_W2B);
    unsigned short* W3b = (unsigned short*)(ws + OFF_W3B);
    float* abT  = (float*)(ws + OFF_ABT);
    float* s1   = (float*)(ws + OFF_S1);
    float* t1   = (float*)(ws + OFF_T1);
    float* gS2  = (float*)(ws + OFF_ST2);
    float* gQ2  = (float*)(ws + OFF_ST2 + 4096);
    float* gS3  = (float*)(ws + OFF_ST3);
    float* gQ3  = (float*)(ws + OFF_ST3 + 2048);
    float* s2 = (float*)(ws + OFF_S2);
    float* t2 = (float*)(ws + OFF_T2);
    float* s3 = (float*)(ws + OFF_S3);
    float* t3 = (float*)(ws + OFF_T3);
    float2* part = (float2*)(ws + OFF_P1);
    unsigned short* h2T = (unsigned short*)(ws + OFF_H2T);
    unsigned short* h3T = (unsigned short*)(ws + OFF_H3T);
    float* out = (float*)d_out;

    hipMemsetAsync(ws + OFF_ST2, 0, 12288, stream);

    k0_pairmean_T<<<16, 256, 0, stream>>>(feats, fT);
    kt_prep<<<672, 256, 0, stream>>>(W1, W2, W3, W1T, W2b, W3b);
    k1_gemm<<<dim3(16, 8), 256, 0, stream>>>(W1T, fT, abT, part);
    k1b_stats<<<1, 512, 0, stream>>>(part, g1, be1, s1, t1);
    k2_mfma<<<dim3(2, 256, 4), 256, 0, stream>>>(abT, W2b, s1, t1, h2T, gS2, gQ2);
    kbnparam<<<1, 128, 0, stream>>>(gS2, gQ2, g2, be2, s2, t2, 128, 1.f / 262144.f);
    k3_mfma<<<dim3(256, 4), 256, 0, stream>>>(h2T, W3b, s2, t2, h3T, gS3, gQ3);
    kbnparam<<<1, 64, 0, stream>>>(gS3, gQ3, g3, be3, s3, t3, 64, 1.f / 262144.f);
    k4_final<<<dim3(256, 4), 256, 0, stream>>>(h3T, W4, s3, t3, b4, out);
}